// Round 10
// baseline (274.967 us; speedup 1.0000x reference)
//
#include <hip/hip_runtime.h>
#include <math.h>

#define N_ 32
#define T_ 2048
#define E_ 512
#define D_ 1024
#define U_ 256

typedef __attribute__((ext_vector_type(8))) short bf16x8;
typedef __attribute__((ext_vector_type(16))) float f32x16;

__device__ __forceinline__ short f2bf_rne(float x) {
  unsigned int u = __float_as_uint(x);
  unsigned int r = u + 0x7FFFu + ((u >> 16) & 1u);
  return (short)(r >> 16);
}
__device__ __forceinline__ short f2bf_trunc(float x) {
  return (short)(__float_as_uint(x) >> 16);
}
__device__ __forceinline__ float bf2f(short h) {
  return __uint_as_float(((unsigned int)(unsigned short)h) << 16);
}
// tanh via hw exp2+rcp: tanh(x) = 1 - 2/(e^{2x}+1); saturates correctly at +-inf
__device__ __forceinline__ float fast_tanh(float x) {
  float t = exp2f(x * 2.8853900817779268f);   // e^{2x}, v_exp_f32
  return 1.0f - 2.0f * __builtin_amdgcn_rcpf(t + 1.0f);
}
__device__ __forceinline__ float fast_sigmoid(float w) {
  return __builtin_amdgcn_rcpf(1.0f + exp2f(-1.4426950408889634f * w));
}

// direct global->LDS DMA, 16B per lane. dst must be the wave-uniform lane-0
// base (HW adds lane*16); src is per-lane.
__device__ __forceinline__ void gload_lds16(const float* src, void* dst) {
  __builtin_amdgcn_global_load_lds(
      (const __attribute__((address_space(1))) void*)src,
      (__attribute__((address_space(3))) void*)dst, 16, 0, 0);
}

// ---------------- K1: Wk -> bf16 hi/lo B-fragments (WGs 0..63)
//                 + proj_q partials (WGs 64..191) ----------------
// frag f = (kk*8+ub)*64+lane : u = ub*32+(lane&31), e = kk*16+(lane>>5)*8+j, kk=0..31
__global__ __launch_bounds__(256) void prep_kernel(
    const float* __restrict__ Wk, const float* __restrict__ queries,
    const float* __restrict__ Wq, bf16x8* __restrict__ whiP,
    bf16x8* __restrict__ wloP, float* __restrict__ pq_part) {
  const int wg = blockIdx.x, tid = threadIdx.x;
  if (wg < 64) {
    const int fid = wg * 256 + tid;
    const int lane = fid & 63;
    const int ub = (fid >> 6) & 7;
    const int kc = (fid >> 9) & 3;
    const int c = fid >> 11;
    const int u = ub * 32 + (lane & 31);
    const int e0 = c * 64 + kc * 16 + (lane >> 5) * 8;
    bf16x8 H, L;
#pragma unroll
    for (int j = 0; j < 8; ++j) {
      float x = Wk[(size_t)(e0 + j) * U_ + u];   // lanes&31 consecutive over u
      short h = f2bf_trunc(x);
      H[j] = h;
      L[j] = f2bf_rne(x - bf2f(h));
    }
    whiP[fid] = H;
    wloP[fid] = L;
  } else {
    const int ch = (wg - 64) & 3;
    const int bb = (wg - 64) >> 2;
    const int d0 = ch * 256;
    const float* q = queries + bb * D_ + d0;
    const float* wq = Wq + (size_t)d0 * U_ + tid;
    float acc = 0.f;
#pragma unroll 8
    for (int d = 0; d < 256; ++d)
      acc = fmaf(q[d], wq[(size_t)d * U_], acc);   // q[d] wave-uniform
    pq_part[(bb * 4 + ch) * U_ + tid] = acc;
  }
}

// ---------------- K2: score, gl_lds staging + WAVE-PER-ROW-BLOCK mapping -----
// Grid 512 (T/128 x N); WG 256 = 4 waves; WG tile 128t x 256u.
// vs r9 (83us, VALUBusy 34%): wave ty now owns rows [32ty,32ty+32) x ALL 256u
// (acc[8] = 128 AGPRs, same MFMA count) instead of all 128 rows x 64u. The A
// work per wave (ds_read + fp32->bf16 hi/lo convert) was identical across the
// 4 waves in r9 — 4x redundant, the doubled-VALUBusy bottleneck. Now it's
// disjoint: conversion and A-reads /4; B-frag loads x4 (L2-resident pool,
// issue-cheap). Epilogue: each row's full u-sum lives in one wave -> 8-term
// tanh sum + 32-lane shuffle, direct p_choose write (smem_w gone). Per-MFMA
// accumulation order bit-identical to r2/r9; only the epilogue u-sum
// association changes (exact f32 terms, threshold headroom 7x).
__global__ __launch_bounds__(256, 2) void score_kernel(
    const float* __restrict__ memory, const bf16x8* __restrict__ whiP,
    const bf16x8* __restrict__ wloP, const float* __restrict__ pq_part,
    const float* __restrict__ v, float* __restrict__ p_choose) {
  __shared__ float sAf[2][128 * 32];   // 2 x 16 KB fp32 tiles

  const int b = blockIdx.y;
  const int t0 = blockIdx.x * 128;
  const int tid = threadIdx.x;
  const int lane = tid & 63;
  const int ty = tid >> 6;             // wave id = row-block (mt)
  const int l31 = lane & 31;
  const int half = lane >> 5;

  f32x16 acc[8];
#pragma unroll
  for (int nt = 0; nt < 8; ++nt)
#pragma unroll
    for (int r = 0; r < 16; ++r) acc[nt][r] = 0.f;

  // staging identical to r9: instruction i covers linear 16B chunks
  // C = (ty*4+i)*64 + lane of the 128x32-float tile; source pre-swizzled so
  // the linear LDS write lands in slot-XOR layout (both-sides rule).
  const float* gsrc[4];
  int ldsoff[4];
#pragma unroll
  for (int i = 0; i < 4; ++i) {
    const int C = (ty * 4 + i) * 64 + lane;
    const int r = C >> 3;
    const int sl = (C & 7) ^ (r & 7);
    gsrc[i] = memory + ((size_t)(b * T_ + t0 + r)) * E_ + sl * 4;
    ldsoff[i] = (ty * 4 + i) * 1024;
  }

  auto do_stage = [&](int buf, int itn) {
    const int co = itn * 32;
#pragma unroll
    for (int i = 0; i < 4; ++i)
      gload_lds16(gsrc[i] + co, (char*)&sAf[buf][0] + ldsoff[i]);
  };

  do_stage(0, 0);
  __syncthreads();

  // this wave's A row in LDS (fixed across iters)
  const int m = ty * 32 + l31;
  const int msw = m & 7;

  for (int it = 0; it < 16; ++it) {
    if (it < 15) do_stage((it + 1) & 1, it + 1);

    const char* base = (const char*)&sAf[it & 1][0];
    const char* rowp = base + (size_t)m * 128;
#pragma unroll
    for (int kc = 0; kc < 2; ++kc) {
      // A frag: 8 floats -> hi/lo bf16 (converted ONCE, wave-disjoint rows)
      const int ls0 = half * 2 + kc * 4;
      float4 f0 = *(const float4*)(rowp + ((ls0 ^ msw) * 16));
      float4 f1 = *(const float4*)(rowp + (((ls0 + 1) ^ msw) * 16));
      float xs[8] = {f0.x, f0.y, f0.z, f0.w, f1.x, f1.y, f1.z, f1.w};
      bf16x8 ah, al;
#pragma unroll
      for (int i = 0; i < 8; ++i) {
        short h = f2bf_trunc(xs[i]);
        ah[i] = h;
        al[i] = f2bf_rne(xs[i] - bf2f(h));
      }
      // B frags: all 8 u-blocks (contiguous 8KB region, L2-resident)
      const bf16x8* bhp = whiP + (size_t)((it * 2 + kc) * 8) * 64 + lane;
      const bf16x8* blp = wloP + (size_t)((it * 2 + kc) * 8) * 64 + lane;
#pragma unroll
      for (int nt = 0; nt < 8; ++nt) {
        bf16x8 bh = bhp[nt * 64];
        bf16x8 bl = blp[nt * 64];
        acc[nt] = __builtin_amdgcn_mfma_f32_32x32x16_bf16(ah, bh, acc[nt], 0, 0, 0);
        acc[nt] = __builtin_amdgcn_mfma_f32_32x32x16_bf16(ah, bl, acc[nt], 0, 0, 0);
        acc[nt] = __builtin_amdgcn_mfma_f32_32x32x16_bf16(al, bh, acc[nt], 0, 0, 0);
      }
    }
    __syncthreads();
  }

  // epilogue: w[row] = sum_u tanh(score + pq[u]) * v[u]; p = sigmoid(w).
  // lane covers u = nt*32 + l31 for nt=0..7; 32-lane tree completes 256 u.
  float pq[8], vv[8];
#pragma unroll
  for (int nt = 0; nt < 8; ++nt) {
    const int u = nt * 32 + l31;
    float s = 0.f;
#pragma unroll
    for (int c = 0; c < 4; ++c) s += pq_part[(b * 4 + c) * U_ + u];
    pq[nt] = s;
    vv[nt] = v[u];
  }
#pragma unroll
  for (int r = 0; r < 16; ++r) {
    float s = 0.f;
#pragma unroll
    for (int nt = 0; nt < 8; ++nt)
      s += fast_tanh(acc[nt][r] + pq[nt]) * vv[nt];
#pragma unroll
    for (int off = 1; off < 32; off <<= 1) s += __shfl_xor(s, off, 64);
    if (l31 == 0) {
      const int row = ty * 32 + (r & 3) + 8 * (r >> 2) + 4 * half;
      p_choose[b * T_ + t0 + row] = fast_sigmoid(s);
    }
  }
}

// ---------------- K3: monotonic scan per batch row + zero ctx_out ----------------
__device__ __forceinline__ float block_incl_scan(float val, float* sbuf, int tid) {
  float x = val;
  sbuf[tid] = x;
  __syncthreads();
#pragma unroll
  for (int off = 1; off < 256; off <<= 1) {
    float t = (tid >= off) ? sbuf[tid - off] : 0.f;
    __syncthreads();
    x += t;
    sbuf[tid] = x;
    __syncthreads();
  }
  return x;
}

__global__ __launch_bounds__(256) void scan_kernel(
    const float* __restrict__ p_choose, const float* __restrict__ prev,
    float* __restrict__ align_out, float* __restrict__ ctx_out) {
  __shared__ float sbuf[256];
  const int b = blockIdx.x, tid = threadIdx.x;
  // zero this batch's ctx row (d_out is poisoned before every call)
  ctx_out[b * E_ + tid] = 0.f;
  ctx_out[b * E_ + 256 + tid] = 0.f;
  const int base = b * T_ + tid * 8;
  float4 p0 = *(const float4*)(p_choose + base);
  float4 p1 = *(const float4*)(p_choose + base + 4);
  float p[8] = {p0.x, p0.y, p0.z, p0.w, p1.x, p1.y, p1.z, p1.w};
  float s[8];
  float run = 0.f;
#pragma unroll
  for (int k = 0; k < 8; ++k) {
    float x = 1.0f - p[k];
    x = fminf(fmaxf(x, 1e-20f), 1.0f);
    run += logf(x);
    s[k] = run;
  }
  float incl = block_incl_scan(run, sbuf, tid);
  float excl = incl - run;
  float cp[8];
#pragma unroll
  for (int k = 0; k < 8; ++k)
    cp[k] = expf(excl + (k ? s[k - 1] : 0.f));
  float4 r0 = *(const float4*)(prev + base);
  float4 r1 = *(const float4*)(prev + base + 4);
  float pr[8] = {r0.x, r0.y, r0.z, r0.w, r1.x, r1.y, r1.z, r1.w};
  float s2[8];
  float run2 = 0.f;
#pragma unroll
  for (int k = 0; k < 8; ++k) {
    float d = fminf(fmaxf(cp[k], 1e-10f), 1.0f);
    run2 += pr[k] / d;
    s2[k] = run2;
  }
  float incl2 = block_incl_scan(run2, sbuf, tid);
  float excl2 = incl2 - run2;
#pragma unroll
  for (int k = 0; k < 8; ++k)
    p[k] = p[k] * cp[k] * (excl2 + s2[k]);
  *(float4*)(align_out + base) = make_float4(p[0], p[1], p[2], p[3]);
  *(float4*)(align_out + base + 4) = make_float4(p[4], p[5], p[6], p[7]);
}

// ---------------- K4: contexts = alignments . memory (atomic accumulate) ----------
// 512 WGs: wg -> (b, 128-row chunk); each half-WG does 64 rows x full E.
// Unroll-4 with batched loads: 4 float4 + 4 align scalars in flight per thread.
__global__ __launch_bounds__(256) void ctx_kernel(
    const float* __restrict__ memory, const float* __restrict__ align,
    float* __restrict__ ctx_out) {
  const int wg = blockIdx.x, tid = threadIdx.x;
  const int b = wg >> 4;
  const int t0 = (wg & 15) * 128 + (tid >> 7) * 64;
  const int col = (tid & 127) * 4;
  const float* mrow = memory + ((size_t)(b * T_ + t0)) * E_ + col;
  const float* arow = align + b * T_ + t0;
  float4 a = make_float4(0.f, 0.f, 0.f, 0.f);
  for (int t = 0; t < 64; t += 4) {
    float4 m0 = *(const float4*)(mrow + (size_t)(t + 0) * E_);
    float4 m1 = *(const float4*)(mrow + (size_t)(t + 1) * E_);
    float4 m2 = *(const float4*)(mrow + (size_t)(t + 2) * E_);
    float4 m3 = *(const float4*)(mrow + (size_t)(t + 3) * E_);
    float a0 = arow[t], a1 = arow[t + 1], a2 = arow[t + 2], a3 = arow[t + 3];
    a.x = fmaf(a0, m0.x, a.x); a.y = fmaf(a0, m0.y, a.y);
    a.z = fmaf(a0, m0.z, a.z); a.w = fmaf(a0, m0.w, a.w);
    a.x = fmaf(a1, m1.x, a.x); a.y = fmaf(a1, m1.y, a.y);
    a.z = fmaf(a1, m1.z, a.z); a.w = fmaf(a1, m1.w, a.w);
    a.x = fmaf(a2, m2.x, a.x); a.y = fmaf(a2, m2.y, a.y);
    a.z = fmaf(a2, m2.z, a.z); a.w = fmaf(a2, m2.w, a.w);
    a.x = fmaf(a3, m3.x, a.x); a.y = fmaf(a3, m3.y, a.y);
    a.z = fmaf(a3, m3.z, a.z); a.w = fmaf(a3, m3.w, a.w);
  }
  float* dst = ctx_out + b * E_ + col;
  atomicAdd(dst + 0, a.x);
  atomicAdd(dst + 1, a.y);
  atomicAdd(dst + 2, a.z);
  atomicAdd(dst + 3, a.w);
}

// ---------------- launch ----------------
extern "C" void kernel_launch(void* const* d_in, const int* in_sizes, int n_in,
                              void* d_out, int out_size, void* d_ws, size_t ws_size,
                              hipStream_t stream) {
  (void)in_sizes; (void)n_in; (void)out_size; (void)ws_size;
  const float* queries = (const float*)d_in[0];
  const float* prev    = (const float*)d_in[1];
  const float* memory  = (const float*)d_in[2];
  const float* Wq      = (const float*)d_in[3];
  const float* Wk      = (const float*)d_in[4];
  const float* v       = (const float*)d_in[5];

  float* out = (float*)d_out;
  float* ctx_out = out;              // [N,E]
  float* align_out = out + N_ * E_;  // [N,T]

  // ws layout (float slots): whiP [0,65536)  wloP [65536,131072)
  //   p_choose [131072,196608)  pq_part [196608,200704)
  float* ws = (float*)d_ws;
  bf16x8* whiP    = (bf16x8*)ws;
  bf16x8* wloP    = (bf16x8*)(ws + 65536);
  float* p_choose = ws + 131072;
  float* pq_part  = ws + 196608;

  prep_kernel<<<dim3(64 + 128), 256, 0, stream>>>(Wk, queries, Wq, whiP, wloP, pq_part);
  score_kernel<<<dim3(T_ / 128, N_), 256, 0, stream>>>(memory, whiP, wloP, pq_part, v, p_choose);
  scan_kernel<<<dim3(N_), 256, 0, stream>>>(p_choose, prev, align_out, ctx_out);
  ctx_kernel<<<dim3(512), 256, 0, stream>>>(memory, align_out, ctx_out);
}